// Round 1
// baseline (690.243 us; speedup 1.0000x reference)
//
#include <hip/hip_runtime.h>
#include <hip/hip_bf16.h>
#include <stdint.h>

// Problem constants (fixed by setup_inputs)
#define FCB 2            // codebooks
#define BB 16            // batch
#define NN 256           // tokens per (b)
#define EDIM 1024
#define CC 512           // channels per codebook
#define NE 4096          // prototypes per codebook
#define TOKENS (BB*FCB*NN)   // 8192
#define ROWS (FCB*NE)        // 8192 emb rows
#define OUT_LOSS (BB*NN*EDIM)   // 4194304 (also the element count for the mean)
#define OUT_IDX  (OUT_LOSS + 1)

// monotonic float->uint mapping for packed atomic argmax
__device__ __forceinline__ unsigned int ford(float v) {
    unsigned int u = __float_as_uint(v);
    return (u & 0x80000000u) ? ~u : (u | 0x80000000u);
}

// ---- kernel 1: inv_norm per emb row; zero best[]; zero loss ----------------
__global__ __launch_bounds__(256) void init_kernel(
    const float* __restrict__ emb, float* __restrict__ inv_norm,
    unsigned long long* __restrict__ best, float* __restrict__ out)
{
    int r = blockIdx.x;            // 0..8191
    int tid = threadIdx.x;
    const float* row = emb + (size_t)r * CC;
    float a = row[tid], b = row[tid + 256];
    float ss = a*a + b*b;
    #pragma unroll
    for (int off = 32; off; off >>= 1) ss += __shfl_down(ss, off);
    __shared__ float part[4];
    if ((tid & 63) == 0) part[tid >> 6] = ss;
    __syncthreads();
    if (tid == 0) {
        float t = part[0] + part[1] + part[2] + part[3];
        inv_norm[r] = 1.0f / fmaxf(sqrtf(t), 1e-12f);
        best[r] = 0ull;                 // any real packed value beats 0
        if (r == 0) out[OUT_LOSS] = 0.0f;
    }
}

// ---- kernel 2: fp32 tiled GEMM (tokens x protos x 512) + fused argmax ------
// C[t,m] = z_t . emb_m ; argmax_m C[t,m]*inv_norm[m]
#define TT 64
#define TN 64
#define KB 32

__global__ __launch_bounds__(256) void gemm_argmax(
    const float* __restrict__ z, const float* __restrict__ emb,
    const float* __restrict__ inv_norm, unsigned long long* __restrict__ best)
{
    const int f  = blockIdx.z;        // codebook
    const int t0 = blockIdx.y * TT;   // token base within codebook (0..4095)
    const int m0 = blockIdx.x * TN;   // proto base within codebook
    const int tid = threadIdx.x;
    const int tx = tid & 15, ty = tid >> 4;   // 16x16 thread grid, 4x4 microtile
    const int lrow = tid >> 3;        // 0..31 (staging row)
    const int lk4  = (tid & 7) * 4;   // 0..28 step 4 (staging k)

    __shared__ float As[KB][TT];      // [k][token]
    __shared__ float Bs[KB][TN];      // [k][proto]

    float acc[4][4];
    #pragma unroll
    for (int i = 0; i < 4; ++i)
        #pragma unroll
        for (int j = 0; j < 4; ++j) acc[i][j] = 0.f;

    for (int kb = 0; kb < CC; kb += KB) {
        #pragma unroll
        for (int h = 0; h < 2; ++h) {
            int r = lrow + h * 32;
            int u = t0 + r;                  // token within codebook
            int b = u >> 8, n = u & 255;
            const float4 va = *(const float4*)(z + ((size_t)(b*NN + n))*EDIM + f*CC + kb + lk4);
            As[lk4+0][r] = va.x; As[lk4+1][r] = va.y; As[lk4+2][r] = va.z; As[lk4+3][r] = va.w;
            const float4 vb = *(const float4*)(emb + ((size_t)(f*NE + m0 + r))*CC + kb + lk4);
            Bs[lk4+0][r] = vb.x; Bs[lk4+1][r] = vb.y; Bs[lk4+2][r] = vb.z; Bs[lk4+3][r] = vb.w;
        }
        __syncthreads();
        #pragma unroll
        for (int kk = 0; kk < KB; ++kk) {
            float4 a4 = *(const float4*)&As[kk][ty*4];
            float4 b4 = *(const float4*)&Bs[kk][tx*4];
            float ar[4] = {a4.x, a4.y, a4.z, a4.w};
            float br[4] = {b4.x, b4.y, b4.z, b4.w};
            #pragma unroll
            for (int i = 0; i < 4; ++i)
                #pragma unroll
                for (int j = 0; j < 4; ++j)
                    acc[i][j] = fmaf(ar[i], br[j], acc[i][j]);
        }
        __syncthreads();
    }

    float inm[4];
    #pragma unroll
    for (int j = 0; j < 4; ++j) inm[j] = inv_norm[f*NE + m0 + tx*4 + j];

    #pragma unroll
    for (int i = 0; i < 4; ++i) {
        float v = acc[i][0] * inm[0];
        int id = m0 + tx*4;
        #pragma unroll
        for (int j = 1; j < 4; ++j) {
            float w = acc[i][j] * inm[j];
            if (w > v) { v = w; id = m0 + tx*4 + j; }   // strict > keeps lowest idx on tie
        }
        // reduce across the 16 lanes sharing this token row (contiguous lanes)
        #pragma unroll
        for (int off = 8; off; off >>= 1) {
            float ov = __shfl_down(v, off, 16);
            int   oi = __shfl_down(id, off, 16);
            if (ov > v || (ov == v && oi < id)) { v = ov; id = oi; }
        }
        if (tx == 0) {
            int u = t0 + ty*4 + i;
            int b = u >> 8, n = u & 255;
            int gt = ((b*FCB + f) << 8) + n;   // global token id, (b,f,n) order
            unsigned long long p = ((unsigned long long)ford(v) << 32)
                                 | (unsigned int)(~(unsigned int)id);   // tie -> lower idx wins
            atomicMax(best + gt, p);
        }
    }
}

// ---- kernel 3: gather z_q, write outputs, accumulate loss ------------------
__global__ __launch_bounds__(256) void epilogue_kernel(
    const float* __restrict__ z, const float* __restrict__ emb,
    const float* __restrict__ inv_norm, const unsigned long long* __restrict__ best,
    float* __restrict__ out)
{
    int t = blockIdx.x;                // global token (b,f,n)
    int tid = threadIdx.x;
    int n = t & 255;
    int f = (t >> 8) & 1;
    int b = t >> 9;
    unsigned long long p = best[t];
    int idx = (int)(~(unsigned int)p);         // in [0, 4096): codebook-0 rows (faithful quirk)
    const float* zrow = z + ((size_t)(b*NN + n))*EDIM + f*CC;
    const float* erow = emb + (size_t)idx * CC;
    float inm = inv_norm[idx];
    float* orow = out + ((size_t)(b*NN + n))*EDIM + f*CC;
    float s1 = 0.f, s2 = 0.f;
    #pragma unroll
    for (int h = 0; h < 2; ++h) {
        int c = tid + h*256;
        float zv = zrow[c];
        float ev = erow[c] * inm;      // z_q component (unit row)
        orow[c] = ev;                  // z_q_st forward == z_q
        s1 = fmaf(zv, zv, s1);
        s2 = fmaf(zv, ev, s2);
    }
    #pragma unroll
    for (int off = 32; off; off >>= 1) {
        s1 += __shfl_down(s1, off);
        s2 += __shfl_down(s2, off);
    }
    __shared__ float p1[4], p2[4];
    if ((tid & 63) == 0) { p1[tid >> 6] = s1; p2[tid >> 6] = s2; }
    __syncthreads();
    if (tid == 0) {
        float S1 = p1[0] + p1[1] + p1[2] + p1[3];
        float S2 = p2[0] + p2[1] + p2[2] + p2[3];
        float cosv = S2 / fmaxf(sqrtf(S1), 1e-12f);   // zn . z_q
        // loss = 1.25 * mean((z_q - zn)^2); per token: (2 - 2cos)/N_elems
        atomicAdd(out + OUT_LOSS, (1.25f / (float)OUT_LOSS) * (2.0f - 2.0f * cosv));
        out[OUT_IDX + t] = (float)idx;                // indices read back as float
    }
}

extern "C" void kernel_launch(void* const* d_in, const int* in_sizes, int n_in,
                              void* d_out, int out_size, void* d_ws, size_t ws_size,
                              hipStream_t stream) {
    const float* z   = (const float*)d_in[0];
    const float* emb = (const float*)d_in[1];
    float* out = (float*)d_out;
    float* inv_norm = (float*)d_ws;                                   // 8192 f32
    unsigned long long* best =
        (unsigned long long*)((char*)d_ws + ROWS * sizeof(float));    // 8192 u64

    init_kernel<<<ROWS, 256, 0, stream>>>(emb, inv_norm, best, out);
    gemm_argmax<<<dim3(NE/TN, NE/TT, FCB), 256, 0, stream>>>(z, emb, inv_norm, best);
    epilogue_kernel<<<TOKENS, 256, 0, stream>>>(z, emb, inv_norm, best, out);
}

// Round 2
// 295.402 us; speedup vs baseline: 2.3366x; 2.3366x over previous
//
#include <hip/hip_runtime.h>
#include <hip/hip_bf16.h>
#include <stdint.h>

// Problem constants (fixed by setup_inputs)
#define FCB 2            // codebooks
#define BB 16            // batch
#define NN 256           // tokens per (b)
#define EDIM 1024
#define CC 512           // channels per codebook
#define NE 4096          // prototypes per codebook
#define TOKENS (BB*FCB*NN)   // 8192
#define ROWS (FCB*NE)        // 8192 emb rows
#define OUT_LOSS (BB*NN*EDIM)   // 4194304 (also the element count for the mean)
#define OUT_IDX  (OUT_LOSS + 1)

typedef __attribute__((ext_vector_type(8))) short bf16x8;   // 8 bf16 = 4 VGPRs (MFMA A/B frag)
typedef __attribute__((ext_vector_type(4))) float f32x4;    // MFMA C/D frag

// monotonic float->uint mapping for packed atomic argmax
__device__ __forceinline__ unsigned int ford(float v) {
    unsigned int u = __float_as_uint(v);
    return (u & 0x80000000u) ? ~u : (u | 0x80000000u);
}

// ---------------------------------------------------------------------------
// ws layout:
//   [0]        inv_norm   8192 f32   (32 KB)
//   [32768]    best       8192 u64   (64 KB)
//   [98304]    z_hi  2*4096*512 bf16 (8 MB)   packed fragment-order
//   [+8MB]     z_lo
//   [+16MB]    e_hi
//   [+24MB]    e_lo
// Packed layout (per part): elem index = ((f*256 + R)*64 + Q)*128 + m*8 + j
//   R = 16-row tile (token/16 or protorow/16), Q = 8-elem k-chunk, m = row in
//   tile, j = elem in chunk.  This makes both the global_load_lds staging AND
//   the ds_read_b128 fragment reads perfectly lane-linear (lane l <-> l*16 B).
// ---------------------------------------------------------------------------

// ---- pack kernel: fp32 -> (hi, lo) bf16 split in fragment-packed order -----
__global__ __launch_bounds__(256) void pack_split(
    const float* __restrict__ src, short* __restrict__ hi, short* __restrict__ lo,
    int row_stride, int f_row_off, int f_col_off)
{
    int u = blockIdx.x * 256 + threadIdx.x;   // [0, 2*256*64*16) = 524288
    int m = u & 15;
    int Q = (u >> 4) & 63;
    int R = (u >> 10) & 255;
    int f = u >> 18;
    int row = R * 16 + m;
    const float* s = src + (size_t)(f * f_row_off + row) * row_stride
                         + f * f_col_off + Q * 8;
    float4 v0 = *(const float4*)s;
    float4 v1 = *(const float4*)(s + 4);
    float vv[8] = {v0.x, v0.y, v0.z, v0.w, v1.x, v1.y, v1.z, v1.w};
    bf16x8 h8, l8;
    #pragma unroll
    for (int j = 0; j < 8; ++j) {
        __hip_bfloat16 hb = __float2bfloat16(vv[j]);
        float r = vv[j] - __bfloat162float(hb);   // exact residual
        __hip_bfloat16 lb = __float2bfloat16(r);
        h8[j] = *(short*)&hb;
        l8[j] = *(short*)&lb;
    }
    *(bf16x8*)(hi + (size_t)u * 8) = h8;
    *(bf16x8*)(lo + (size_t)u * 8) = l8;
}

// ---- init: inv_norm per emb row; zero best[]; zero loss --------------------
__global__ __launch_bounds__(256) void init_kernel(
    const float* __restrict__ emb, float* __restrict__ inv_norm,
    unsigned long long* __restrict__ best, float* __restrict__ out)
{
    int r = blockIdx.x;            // 0..8191
    int tid = threadIdx.x;
    const float* row = emb + (size_t)r * CC;
    float a = row[tid], b = row[tid + 256];
    float ss = a*a + b*b;
    #pragma unroll
    for (int off = 32; off; off >>= 1) ss += __shfl_down(ss, off);
    __shared__ float part[4];
    if ((tid & 63) == 0) part[tid >> 6] = ss;
    __syncthreads();
    if (tid == 0) {
        float t = part[0] + part[1] + part[2] + part[3];
        inv_norm[r] = 1.0f / fmaxf(sqrtf(t), 1e-12f);
        best[r] = 0ull;                 // any real packed value beats 0
        if (r == 0) out[OUT_LOSS] = 0.0f;
    }
}

// ---- bf16x3 split MFMA GEMM + fused argmax ---------------------------------
// C[t,m] = z_t . e_m  computed as Ah*Bh + Ah*Bl + Al*Bh (error ~1e-7 on cos).
// 128x128 tile, BK=32, 4 waves (2x2), each wave 4x4 of 16x16x32 MFMA.
__global__ __launch_bounds__(256, 2) void gemm_mfma(
    const short* __restrict__ zh, const short* __restrict__ zl,
    const short* __restrict__ eh, const short* __restrict__ el,
    const float* __restrict__ inv_norm, unsigned long long* __restrict__ best)
{
    __shared__ char smem[32768];      // A_hi | A_lo | B_hi | B_lo, 8 KB each
    const int f  = blockIdx.z;
    const int t0 = blockIdx.y * 128;  // token base within codebook
    const int m0 = blockIdx.x * 128;  // proto base within codebook
    const int tid  = threadIdx.x;
    const int wave = tid >> 6, lane = tid & 63;
    const int wm = wave & 1, wn = wave >> 1;

    // staging: wave w DMAs part w (8 instr x 1 KB = 8 KB per step)
    const short* gsrc; int lbase; int row0;
    if      (wave == 0) { gsrc = zh; lbase = 0;     row0 = t0 >> 4; }
    else if (wave == 1) { gsrc = zl; lbase = 8192;  row0 = t0 >> 4; }
    else if (wave == 2) { gsrc = eh; lbase = 16384; row0 = m0 >> 4; }
    else                { gsrc = el; lbase = 24576; row0 = m0 >> 4; }

    f32x4 acc[4][4] = {};

    for (int step = 0; step < 16; ++step) {
        const int qb = step * 4;      // k-chunk base (k = qb*8)
        __syncthreads();              // previous compute done before overwrite
        #pragma unroll
        for (int j = 0; j < 8; ++j) {
            const short* g = gsrc
                + (((size_t)f * 256 + row0 + j) * 64 + qb) * 128
                + (size_t)lane * 8;
            __builtin_amdgcn_global_load_lds(
                (const __attribute__((address_space(1))) void*)g,
                (__attribute__((address_space(3))) void*)(smem + lbase + j * 1024),
                16, 0, 0);
        }
        __syncthreads();              // staged data visible to all waves

        bf16x8 ah[4], al[4], bh[4], bl[4];
        #pragma unroll
        for (int i = 0; i < 4; ++i) {
            int sa = wm * 4 + i, sb = wn * 4 + i;
            ah[i] = *(const bf16x8*)(smem + 0     + sa * 1024 + lane * 16);
            al[i] = *(const bf16x8*)(smem + 8192  + sa * 1024 + lane * 16);
            bh[i] = *(const bf16x8*)(smem + 16384 + sb * 1024 + lane * 16);
            bl[i] = *(const bf16x8*)(smem + 24576 + sb * 1024 + lane * 16);
        }
        #pragma unroll
        for (int i = 0; i < 4; ++i)
            #pragma unroll
            for (int j2 = 0; j2 < 4; ++j2) {
                acc[i][j2] = __builtin_amdgcn_mfma_f32_16x16x32_bf16(ah[i], bh[j2], acc[i][j2], 0, 0, 0);
                acc[i][j2] = __builtin_amdgcn_mfma_f32_16x16x32_bf16(ah[i], bl[j2], acc[i][j2], 0, 0, 0);
                acc[i][j2] = __builtin_amdgcn_mfma_f32_16x16x32_bf16(al[i], bh[j2], acc[i][j2], 0, 0, 0);
            }
    }

    // ---- fused argmax epilogue ----
    // C/D layout (16x16x32): col(N=proto) = lane&15, row(M=token) = (lane>>4)*4 + reg
    float inm[4];
    #pragma unroll
    for (int j2 = 0; j2 < 4; ++j2)
        inm[j2] = inv_norm[f * NE + m0 + wn * 64 + j2 * 16 + (lane & 15)];

    #pragma unroll
    for (int i = 0; i < 4; ++i) {
        #pragma unroll
        for (int r = 0; r < 4; ++r) {
            float v = acc[i][0][r] * inm[0];
            int  id = m0 + wn * 64 + (lane & 15);
            #pragma unroll
            for (int j2 = 1; j2 < 4; ++j2) {
                float w = acc[i][j2][r] * inm[j2];
                int  wi = m0 + wn * 64 + j2 * 16 + (lane & 15);
                if (w > v || (w == v && wi < id)) { v = w; id = wi; }
            }
            // reduce across the 16 contiguous lanes holding this token row
            #pragma unroll
            for (int off = 8; off; off >>= 1) {
                float ov = __shfl_down(v, off, 16);
                int   oi = __shfl_down(id, off, 16);
                if (ov > v || (ov == v && oi < id)) { v = ov; id = oi; }
            }
            if ((lane & 15) == 0) {
                int u = t0 + wm * 64 + i * 16 + (lane >> 4) * 4 + r;
                int b = u >> 8, n = u & 255;
                int gt = ((b * FCB + f) << 8) + n;   // global token id (b,f,n)
                unsigned long long p = ((unsigned long long)ford(v) << 32)
                                     | (unsigned int)(~(unsigned int)id);
                atomicMax(best + gt, p);
            }
        }
    }
}

// ---- epilogue: gather z_q, write outputs, accumulate loss ------------------
__global__ __launch_bounds__(256) void epilogue_kernel(
    const float* __restrict__ z, const float* __restrict__ emb,
    const float* __restrict__ inv_norm, const unsigned long long* __restrict__ best,
    float* __restrict__ out)
{
    int t = blockIdx.x;                // global token (b,f,n)
    int tid = threadIdx.x;
    int n = t & 255;
    int f = (t >> 8) & 1;
    int b = t >> 9;
    unsigned long long p = best[t];
    int idx = (int)(~(unsigned int)p);         // in [0, 4096): codebook-0 rows (faithful quirk)
    const float* zrow = z + ((size_t)(b*NN + n))*EDIM + f*CC;
    const float* erow = emb + (size_t)idx * CC;
    float inm = inv_norm[idx];
    float* orow = out + ((size_t)(b*NN + n))*EDIM + f*CC;
    float s1 = 0.f, s2 = 0.f;
    #pragma unroll
    for (int h = 0; h < 2; ++h) {
        int c = tid + h*256;
        float zv = zrow[c];
        float ev = erow[c] * inm;      // z_q component (unit row)
        orow[c] = ev;                  // z_q_st forward == z_q
        s1 = fmaf(zv, zv, s1);
        s2 = fmaf(zv, ev, s2);
    }
    #pragma unroll
    for (int off = 32; off; off >>= 1) {
        s1 += __shfl_down(s1, off);
        s2 += __shfl_down(s2, off);
    }
    __shared__ float p1[4], p2[4];
    if ((tid & 63) == 0) { p1[tid >> 6] = s1; p2[tid >> 6] = s2; }
    __syncthreads();
    if (tid == 0) {
        float S1 = p1[0] + p1[1] + p1[2] + p1[3];
        float S2 = p2[0] + p2[1] + p2[2] + p2[3];
        float cosv = S2 / fmaxf(sqrtf(S1), 1e-12f);   // zn . z_q
        // loss = 1.25 * mean((z_q - zn)^2); per token: (2 - 2cos)/N_elems
        atomicAdd(out + OUT_LOSS, (1.25f / (float)OUT_LOSS) * (2.0f - 2.0f * cosv));
        out[OUT_IDX + t] = (float)idx;                // indices read back as float
    }
}

extern "C" void kernel_launch(void* const* d_in, const int* in_sizes, int n_in,
                              void* d_out, int out_size, void* d_ws, size_t ws_size,
                              hipStream_t stream) {
    const float* z   = (const float*)d_in[0];
    const float* emb = (const float*)d_in[1];
    float* out = (float*)d_out;

    char* ws = (char*)d_ws;
    float* inv_norm = (float*)ws;                                  // 32 KB
    unsigned long long* best = (unsigned long long*)(ws + 32768);  // 64 KB
    const size_t PART = (size_t)FCB * NE * CC;                     // 4 Mi elems
    short* z_hi = (short*)(ws + 98304);
    short* z_lo = z_hi + PART;
    short* e_hi = z_lo + PART;
    short* e_lo = e_hi + PART;
    // ws needed: 96 KB + 4 * 8 MB = ~33.6 MB

    // pack z: row = token t (stride EDIM), codebook selects column block f*CC
    pack_split<<<2048, 256, 0, stream>>>(z,   z_hi, z_lo, EDIM, 0,  CC);
    // pack emb: row = f*NE + r (stride CC)
    pack_split<<<2048, 256, 0, stream>>>(emb, e_hi, e_lo, CC,  NE, 0);
    init_kernel<<<ROWS, 256, 0, stream>>>(emb, inv_norm, best, out);
    gemm_mfma<<<dim3(NE/128, NE/128, FCB), 256, 0, stream>>>(
        z_hi, z_lo, e_hi, e_lo, inv_norm, best);
    epilogue_kernel<<<TOKENS, 256, 0, stream>>>(z, emb, inv_norm, best, out);
}

// Round 3
// 198.400 us; speedup vs baseline: 3.4790x; 1.4889x over previous
//
#include <hip/hip_runtime.h>
#include <hip/hip_bf16.h>
#include <stdint.h>

// Problem constants (fixed by setup_inputs)
#define FCB 2            // codebooks
#define BB 16            // batch
#define NN 256           // tokens per (b)
#define EDIM 1024
#define CC 512           // channels per codebook
#define NE 4096          // prototypes per codebook
#define TOKENS (BB*FCB*NN)   // 8192
#define ROWS (FCB*NE)        // 8192 emb rows
#define OUT_LOSS (BB*NN*EDIM)   // 4194304 (also the element count for the mean)
#define OUT_IDX  (OUT_LOSS + 1)

typedef __attribute__((ext_vector_type(8))) short bf16x8;   // 8 bf16 = 4 VGPRs (MFMA A/B frag)
typedef __attribute__((ext_vector_type(4))) float f32x4;    // MFMA C/D frag

// monotonic float->uint mapping for packed atomic argmax
__device__ __forceinline__ unsigned int ford(float v) {
    unsigned int u = __float_as_uint(v);
    return (u & 0x80000000u) ? ~u : (u | 0x80000000u);
}

// ---------------------------------------------------------------------------
// ws layout:
//   [0]        inv_norm   8192 f32   (32 KB)
//   [32768]    best       8192 u64   (64 KB)
//   [98304]    loss_tok   8192 f32   (32 KB)
//   [131072]   z_hi  2*4096*512 bf16 (8 MB)   packed fragment-order
//   [+8MB]     z_lo
//   [+16MB]    e_hi
//   [+24MB]    e_lo
// Packed layout (per part): elem index = ((f*256 + R)*64 + Q)*128 + m*8 + j
// ---------------------------------------------------------------------------

// ---- pack kernel: fp32 -> (hi, lo) bf16 split in fragment-packed order -----
__global__ __launch_bounds__(256) void pack_split(
    const float* __restrict__ src, short* __restrict__ hi, short* __restrict__ lo,
    int row_stride, int f_row_off, int f_col_off)
{
    int u = blockIdx.x * 256 + threadIdx.x;   // [0, 2*256*64*16) = 524288
    int m = u & 15;
    int Q = (u >> 4) & 63;
    int R = (u >> 10) & 255;
    int f = u >> 18;
    int row = R * 16 + m;
    const float* s = src + (size_t)(f * f_row_off + row) * row_stride
                         + f * f_col_off + Q * 8;
    float4 v0 = *(const float4*)s;
    float4 v1 = *(const float4*)(s + 4);
    float vv[8] = {v0.x, v0.y, v0.z, v0.w, v1.x, v1.y, v1.z, v1.w};
    bf16x8 h8, l8;
    #pragma unroll
    for (int j = 0; j < 8; ++j) {
        __hip_bfloat16 hb = __float2bfloat16(vv[j]);
        float r = vv[j] - __bfloat162float(hb);   // exact residual
        __hip_bfloat16 lb = __float2bfloat16(r);
        h8[j] = *(short*)&hb;
        l8[j] = *(short*)&lb;
    }
    *(bf16x8*)(hi + (size_t)u * 8) = h8;
    *(bf16x8*)(lo + (size_t)u * 8) = l8;
}

// ---- init: inv_norm per emb row; zero best[] -------------------------------
__global__ __launch_bounds__(256) void init_kernel(
    const float* __restrict__ emb, float* __restrict__ inv_norm,
    unsigned long long* __restrict__ best)
{
    int r = blockIdx.x;            // 0..8191
    int tid = threadIdx.x;
    const float* row = emb + (size_t)r * CC;
    float a = row[tid], b = row[tid + 256];
    float ss = a*a + b*b;
    #pragma unroll
    for (int off = 32; off; off >>= 1) ss += __shfl_down(ss, off);
    __shared__ float part[4];
    if ((tid & 63) == 0) part[tid >> 6] = ss;
    __syncthreads();
    if (tid == 0) {
        float t = part[0] + part[1] + part[2] + part[3];
        inv_norm[r] = 1.0f / fmaxf(sqrtf(t), 1e-12f);
        best[r] = 0ull;                 // any real packed value beats 0
    }
}

// ---- bf16x3 split MFMA GEMM + fused argmax ---------------------------------
// C[t,m] = z_t . e_m  computed as Ah*Bh + Ah*Bl + Al*Bh (error ~1e-7 on cos).
// 128x128 tile, BK=32, 4 waves (2x2), each wave 4x4 of 16x16x32 MFMA.
__global__ __launch_bounds__(256, 2) void gemm_mfma(
    const short* __restrict__ zh, const short* __restrict__ zl,
    const short* __restrict__ eh, const short* __restrict__ el,
    const float* __restrict__ inv_norm, unsigned long long* __restrict__ best)
{
    __shared__ char smem[32768];      // A_hi | A_lo | B_hi | B_lo, 8 KB each
    const int f  = blockIdx.z;
    const int t0 = blockIdx.y * 128;  // token base within codebook
    const int m0 = blockIdx.x * 128;  // proto base within codebook
    const int tid  = threadIdx.x;
    const int wave = tid >> 6, lane = tid & 63;
    const int wm = wave & 1, wn = wave >> 1;

    // staging: wave w DMAs part w (8 instr x 1 KB = 8 KB per step)
    const short* gsrc; int lbase; int row0;
    if      (wave == 0) { gsrc = zh; lbase = 0;     row0 = t0 >> 4; }
    else if (wave == 1) { gsrc = zl; lbase = 8192;  row0 = t0 >> 4; }
    else if (wave == 2) { gsrc = eh; lbase = 16384; row0 = m0 >> 4; }
    else                { gsrc = el; lbase = 24576; row0 = m0 >> 4; }

    f32x4 acc[4][4] = {};

    for (int step = 0; step < 16; ++step) {
        const int qb = step * 4;      // k-chunk base (k = qb*8)
        __syncthreads();              // previous compute done before overwrite
        #pragma unroll
        for (int j = 0; j < 8; ++j) {
            const short* g = gsrc
                + (((size_t)f * 256 + row0 + j) * 64 + qb) * 128
                + (size_t)lane * 8;
            __builtin_amdgcn_global_load_lds(
                (const __attribute__((address_space(1))) void*)g,
                (__attribute__((address_space(3))) void*)(smem + lbase + j * 1024),
                16, 0, 0);
        }
        __syncthreads();              // staged data visible to all waves

        bf16x8 ah[4], al[4], bh[4], bl[4];
        #pragma unroll
        for (int i = 0; i < 4; ++i) {
            int sa = wm * 4 + i, sb = wn * 4 + i;
            ah[i] = *(const bf16x8*)(smem + 0     + sa * 1024 + lane * 16);
            al[i] = *(const bf16x8*)(smem + 8192  + sa * 1024 + lane * 16);
            bh[i] = *(const bf16x8*)(smem + 16384 + sb * 1024 + lane * 16);
            bl[i] = *(const bf16x8*)(smem + 24576 + sb * 1024 + lane * 16);
        }
        #pragma unroll
        for (int i = 0; i < 4; ++i)
            #pragma unroll
            for (int j2 = 0; j2 < 4; ++j2) {
                acc[i][j2] = __builtin_amdgcn_mfma_f32_16x16x32_bf16(ah[i], bh[j2], acc[i][j2], 0, 0, 0);
                acc[i][j2] = __builtin_amdgcn_mfma_f32_16x16x32_bf16(ah[i], bl[j2], acc[i][j2], 0, 0, 0);
                acc[i][j2] = __builtin_amdgcn_mfma_f32_16x16x32_bf16(al[i], bh[j2], acc[i][j2], 0, 0, 0);
            }
    }

    // ---- fused argmax epilogue ----
    // C/D layout (16x16x32): col(N=proto) = lane&15, row(M=token) = (lane>>4)*4 + reg
    float inm[4];
    #pragma unroll
    for (int j2 = 0; j2 < 4; ++j2)
        inm[j2] = inv_norm[f * NE + m0 + wn * 64 + j2 * 16 + (lane & 15)];

    #pragma unroll
    for (int i = 0; i < 4; ++i) {
        #pragma unroll
        for (int r = 0; r < 4; ++r) {
            float v = acc[i][0][r] * inm[0];
            int  id = m0 + wn * 64 + (lane & 15);
            #pragma unroll
            for (int j2 = 1; j2 < 4; ++j2) {
                float w = acc[i][j2][r] * inm[j2];
                int  wi = m0 + wn * 64 + j2 * 16 + (lane & 15);
                if (w > v || (w == v && wi < id)) { v = w; id = wi; }
            }
            // reduce across the 16 contiguous lanes holding this token row
            #pragma unroll
            for (int off = 8; off; off >>= 1) {
                float ov = __shfl_down(v, off, 16);
                int   oi = __shfl_down(id, off, 16);
                if (ov > v || (ov == v && oi < id)) { v = ov; id = oi; }
            }
            if ((lane & 15) == 0) {
                int u = t0 + wm * 64 + i * 16 + (lane >> 4) * 4 + r;
                int b = u >> 8, n = u & 255;
                int gt = ((b * FCB + f) << 8) + n;   // global token id (b,f,n)
                unsigned long long p = ((unsigned long long)ford(v) << 32)
                                     | (unsigned int)(~(unsigned int)id);
                atomicMax(best + gt, p);
            }
        }
    }
}

// ---- epilogue v2: one wave per token, float4, per-token loss (no atomics) --
__global__ __launch_bounds__(256) void epilogue_kernel(
    const float* __restrict__ z, const float* __restrict__ emb,
    const float* __restrict__ inv_norm, const unsigned long long* __restrict__ best,
    float* __restrict__ out, float* __restrict__ loss_tok)
{
    int t = blockIdx.x * 4 + (threadIdx.x >> 6);   // global token (b,f,n)
    int lane = threadIdx.x & 63;
    int n = t & 255;
    int f = (t >> 8) & 1;
    int b = t >> 9;
    unsigned long long p = best[t];
    int idx = (int)(~(unsigned int)p);         // in [0, 4096): codebook-0 rows (faithful quirk)
    const float* zrow = z + ((size_t)(b*NN + n))*EDIM + f*CC;
    const float* erow = emb + (size_t)idx * CC;
    float inm = inv_norm[idx];
    float* orow = out + ((size_t)(b*NN + n))*EDIM + f*CC;
    float s1 = 0.f, s2 = 0.f;
    #pragma unroll
    for (int h = 0; h < 2; ++h) {
        int c = h * 256 + lane * 4;            // coalesced float4 per lane
        float4 zv = *(const float4*)(zrow + c);
        float4 ev = *(const float4*)(erow + c);
        ev.x *= inm; ev.y *= inm; ev.z *= inm; ev.w *= inm;
        *(float4*)(orow + c) = ev;             // z_q_st forward == z_q
        s1 = fmaf(zv.x, zv.x, fmaf(zv.y, zv.y, fmaf(zv.z, zv.z, fmaf(zv.w, zv.w, s1))));
        s2 = fmaf(zv.x, ev.x, fmaf(zv.y, ev.y, fmaf(zv.z, ev.z, fmaf(zv.w, ev.w, s2))));
    }
    #pragma unroll
    for (int off = 32; off; off >>= 1) {
        s1 += __shfl_down(s1, off);
        s2 += __shfl_down(s2, off);
    }
    if (lane == 0) {
        float cosv = s2 / fmaxf(sqrtf(s1), 1e-12f);   // zn . z_q
        loss_tok[t] = 2.0f - 2.0f * cosv;
        out[OUT_IDX + t] = (float)idx;                // indices read back as float
    }
}

// ---- final: sum per-token losses -> out[OUT_LOSS] --------------------------
__global__ __launch_bounds__(256) void loss_reduce(
    const float* __restrict__ loss_tok, float* __restrict__ out)
{
    int tid = threadIdx.x;
    float s = 0.f;
    #pragma unroll
    for (int h = 0; h < 32; ++h) s += loss_tok[h * 256 + tid];
    #pragma unroll
    for (int off = 32; off; off >>= 1) s += __shfl_down(s, off);
    __shared__ float part[4];
    if ((tid & 63) == 0) part[tid >> 6] = s;
    __syncthreads();
    if (tid == 0) {
        float t = part[0] + part[1] + part[2] + part[3];
        out[OUT_LOSS] = t * (1.25f / (float)OUT_LOSS);
    }
}

extern "C" void kernel_launch(void* const* d_in, const int* in_sizes, int n_in,
                              void* d_out, int out_size, void* d_ws, size_t ws_size,
                              hipStream_t stream) {
    const float* z   = (const float*)d_in[0];
    const float* emb = (const float*)d_in[1];
    float* out = (float*)d_out;

    char* ws = (char*)d_ws;
    float* inv_norm = (float*)ws;                                  // 32 KB
    unsigned long long* best = (unsigned long long*)(ws + 32768);  // 64 KB
    float* loss_tok = (float*)(ws + 98304);                        // 32 KB
    const size_t PART = (size_t)FCB * NE * CC;                     // 4 Mi elems
    short* z_hi = (short*)(ws + 131072);
    short* z_lo = z_hi + PART;
    short* e_hi = z_lo + PART;
    short* e_lo = e_hi + PART;
    // ws needed: 128 KB + 4 * 8 MB = ~33.7 MB

    // pack z: row = token t (stride EDIM), codebook selects column block f*CC
    pack_split<<<2048, 256, 0, stream>>>(z,   z_hi, z_lo, EDIM, 0,  CC);
    // pack emb: row = f*NE + r (stride CC)
    pack_split<<<2048, 256, 0, stream>>>(emb, e_hi, e_lo, CC,  NE, 0);
    init_kernel<<<ROWS, 256, 0, stream>>>(emb, inv_norm, best);
    gemm_mfma<<<dim3(NE/128, NE/128, FCB), 256, 0, stream>>>(
        z_hi, z_lo, e_hi, e_lo, inv_norm, best);
    epilogue_kernel<<<TOKENS/4, 256, 0, stream>>>(z, emb, inv_norm, best, out, loss_tok);
    loss_reduce<<<1, 256, 0, stream>>>(loss_tok, out);
}